// Round 7
// baseline (1128.361 us; speedup 1.0000x reference)
//
#include <hip/hip_runtime.h>
#include <stdint.h>
#include <math.h>

#define TPB   512    // 8 waves/block
#define KTOP  100
#define K1    128    // per-image selection rank cut
#define SR    8      // slice rows

#define HB 272
#define WB 480
#define NSB 34       // 272/8
#define HP 68
#define WP 120
#define NSP 9        // ceil(68/8), last slice 4 rows
#define NB 64

#define BLCAP 32768  // per-image ball survivor list capacity (~15.3k expected)
#define PLCAP 8192   // per-image player survivor list capacity (~0.9k expected)

// ============================================================================
// Validated invariants (rounds 2-6, absmax 0.0):
//  - np-f32 softmax p is a MONOTONE function G of D = fl32(x1-x0);
//    G collapse window |dD| < ~6e-8*e^|D| (< 0.25 for |D| < 13).
//  - NMS: keep iff p >= all 8 neighbors; D-space fast path + exact G on ties.
//  - top-k tie order: (p desc, idx asc)  ==  u64 key (p_bits<<32 | ~idx) desc.
//  - 16-bit D-key rank-128 cut (ties included) contains the exact top-100 set.
// ============================================================================
__device__ __forceinline__ float G_exact(float D) {
    float t = -fabsf(D);
    float etf = (float)exp((double)t);       // correctly-rounded f32 exp
    return (D > 0.0f) ? __fdiv_rn(1.0f, __fadd_rn(etf, 1.0f))
                      : __fdiv_rn(etf, __fadd_rn(1.0f, etf));
}

__device__ __forceinline__ uint32_t flip_f32(float D) {
    uint32_t u = __float_as_uint(D);
    return (u & 0x80000000u) ? ~u : (u | 0x80000000u);
}

// In-place suffix-sum of 256 u32 bins: hist[i] <- sum_{j>=i} hist[j].
// Wave 0 via shuffles; ends with a barrier. (validated round 4)
__device__ __forceinline__ void suffix_scan_256(uint32_t* hist) {
    if (threadIdx.x < 64) {
        int lane = threadIdx.x;
        uint32_t h0 = hist[4*lane+0], h1 = hist[4*lane+1];
        uint32_t h2 = hist[4*lane+2], h3 = hist[4*lane+3];
        uint32_t tot = h0 + h1 + h2 + h3;
        uint32_t run = tot;
        #pragma unroll
        for (int d = 1; d < 64; d <<= 1) {
            uint32_t o = __shfl_down(run, d, 64);
            if (lane + d < 64) run += o;
        }
        uint32_t ab = run - tot;
        hist[4*lane+3] = ab + h3;
        hist[4*lane+2] = ab + h3 + h2;
        hist[4*lane+1] = ab + h3 + h2 + h1;
        hist[4*lane+0] = ab + tot;
    }
    __syncthreads();
}

// Descending bitonic sort of 256 u64 keys; TPB may exceed 256 (guarded).
__device__ void bitonic_sort_256(uint64_t* keys) {
    for (int k = 2; k <= 256; k <<= 1) {
        for (int j = k >> 1; j > 0; j >>= 1) {
            int i = threadIdx.x;
            if (i < 256) {
                int ixj = i ^ j;
                if (ixj > i) {
                    uint64_t ka = keys[i], kb = keys[ixj];
                    bool sw = ((ka < kb) == ((i & k) == 0));
                    if (sw) { keys[i] = kb; keys[ixj] = ka; }
                }
            }
            __syncthreads();
        }
    }
}

// 6-wide row window [c4-1 .. c4+4] from the LDS D-tile (OOB -> -inf).
template<int W>
__device__ __forceinline__ void row6(const float* df, int row, int c4, float* a) {
    const float4 m = ((const float4*)df)[(row * W + c4) >> 2];
    a[1] = m.x; a[2] = m.y; a[3] = m.z; a[4] = m.w;
    a[0] = (c4 > 0)     ? df[row * W + c4 - 1] : -INFINITY;
    a[5] = (c4 + 4 < W) ? df[row * W + c4 + 4] : -INFINITY;
}

// ---- init: zero the 128 per-image append counters --------------------------
__global__ void zeroK(uint32_t* cnts) { cnts[threadIdx.x] = 0; }

// ---- stage 1: D-tile NMS -> append survivors (key16<<32 | gidx) ------------
// One barrier per block. Append counter is per-image (wave-uniform address ->
// compiler aggregates the atomic per wave).
template<int H, int W>
__device__ __forceinline__ void stage1_impl(const float* __restrict__ x,
                                            int s, int b,
                                            uint32_t* __restrict__ cnt,
                                            uint64_t* __restrict__ list,
                                            int lcap, float* df)
{
    constexpr int W4 = W / 4;
    constexpr int tileRows = SR + 2;
    const int r0 = s * SR;
    const int rows = (H - r0 < SR) ? (H - r0) : SR;

    const float*  x0  = x + (size_t)b * 2 * H * W;
    const float*  x1  = x0 + (size_t)H * W;
    const float4* x0v = (const float4*)x0;
    const float4* x1v = (const float4*)x1;
    float4* dfv = (float4*)df;

    // D tile (rows r0-1 .. r0+SR), float4-vectorized; OOB rows -> -inf.
    constexpr int nt4 = tileRows * W4;
    for (int t = threadIdx.x; t < nt4; t += TPB) {
        int tr = t / W4, c4 = t - tr * W4;        // compile-time divisor
        int r = r0 - 1 + tr;
        float4 d4 = make_float4(-INFINITY, -INFINITY, -INFINITY, -INFINITY);
        if (r >= 0 && r < H) {
            float4 a = x0v[r * W4 + c4];
            float4 c = x1v[r * W4 + c4];
            d4.x = __fsub_rn(c.x, a.x);
            d4.y = __fsub_rn(c.y, a.y);
            d4.z = __fsub_rn(c.z, a.z);
            d4.w = __fsub_rn(c.w, a.w);
        }
        dfv[t] = d4;
    }
    __syncthreads();

    // NMS (4 cells/iter), separable column-max form; append survivors.
    const int groups = rows * W4;
    for (int g = threadIdx.x; g < groups; g += TPB) {
        int lr = g / W4, c4 = (g - lr * W4) << 2; // compile-time divisor
        int tr = lr + 1;
        float ap[6], ac[6], an[6], cm[6];
        row6<W>(df, tr - 1, c4, ap);
        row6<W>(df, tr,     c4, ac);
        row6<W>(df, tr + 1, c4, an);
        #pragma unroll
        for (int i = 0; i < 6; ++i) cm[i] = fmaxf(fmaxf(ap[i], ac[i]), an[i]);
        #pragma unroll
        for (int j = 0; j < 4; ++j) {
            float v = ac[j + 1];
            float mx = fmaxf(fmaxf(cm[j], cm[j + 2]), fmaxf(ap[j + 1], an[j + 1]));
            bool keep;
            if (v >= mx) keep = true;                              // exact
            else if (mx - v >= 0.25f && mx < 13.0f) keep = false;  // G distinct
            else keep = (G_exact(v) == G_exact(mx));               // rare tie
            if (keep) {
                uint32_t key16 = flip_f32(v) >> 16;
                uint32_t gidx  = (uint32_t)((r0 + lr) * W + c4 + j);
                uint32_t pos = atomicAdd(cnt, 1u);
                if (pos < (uint32_t)lcap)
                    list[pos] = ((uint64_t)key16 << 32) | gidx;
            }
        }
    }
}

__global__ __launch_bounds__(TPB) void stage1(const float* __restrict__ bmap,
                                              const float* __restrict__ pmap,
                                              uint32_t* __restrict__ cnts,
                                              uint64_t* __restrict__ blist,
                                              uint64_t* __restrict__ plist)
{
    __shared__ float df[(SR + 2) * WB];           // 19200 B (max of both maps)
    const int b = blockIdx.y;
    if (blockIdx.x < NSB)
        stage1_impl<HB, WB>(bmap, blockIdx.x, b, cnts + b,
                            blist + (size_t)b * BLCAP, BLCAP, df);
    else
        stage1_impl<HP, WP>(pmap, blockIdx.x - NSB, b, cnts + NB + b,
                            plist + (size_t)b * PLCAP, PLCAP, df);
}

// ---- stage 2: per-image D16 radix-select -> exact-p rerank -> decode -------
template<int H, int W, bool BALL>
__device__ __forceinline__ void stage2_impl(const float* __restrict__ xmap,
                                            const float* __restrict__ pbbox,
                                            const uint32_t* __restrict__ cnt,
                                            const uint64_t* __restrict__ list,
                                            float* __restrict__ outp, int b,
                                            uint32_t* hist, uint64_t* outb)
{
    __shared__ int s_out;
    __shared__ uint32_t s_bin, s_ab, s_bin2, s_none;
    if (threadIdx.x == 0) { s_out = 0; s_none = 0; }
    if (threadIdx.x < 256) hist[threadIdx.x] = 0;
    __syncthreads();

    const int n = min((int)*cnt, BALL ? BLCAP : PLCAP);

    // Level-1: histogram of key16 high byte.
    for (int t = threadIdx.x; t < n; t += TPB) {
        uint32_t k16 = (uint32_t)(list[t] >> 32);
        atomicAdd(&hist[k16 >> 8], 1u);
    }
    __syncthreads();
    suffix_scan_256(hist);
    if (threadIdx.x < 256) {
        uint32_t si = hist[threadIdx.x];
        uint32_t sn = (threadIdx.x < 255) ? hist[threadIdx.x + 1] : 0u;
        if (threadIdx.x == 0 && si < K1) s_none = 1;
        if (si >= K1 && sn < K1) { s_bin = threadIdx.x; s_ab = sn; }
    }
    __syncthreads();

    uint32_t T16 = 0;
    if (!s_none) {
        const uint32_t b3 = s_bin;
        const uint32_t k2 = K1 - s_ab;
        if (threadIdx.x < 256) hist[threadIdx.x] = 0;
        __syncthreads();
        for (int t = threadIdx.x; t < n; t += TPB) {
            uint32_t k16 = (uint32_t)(list[t] >> 32);
            if ((k16 >> 8) == b3) atomicAdd(&hist[k16 & 255u], 1u);
        }
        __syncthreads();
        suffix_scan_256(hist);
        if (threadIdx.x < 256) {
            uint32_t si = hist[threadIdx.x];
            uint32_t sn = (threadIdx.x < 255) ? hist[threadIdx.x + 1] : 0u;
            if (si >= k2 && sn < k2) s_bin2 = threadIdx.x;
        }
        __syncthreads();
        T16 = (b3 << 8) | s_bin2;
    }

    // Compact finalists (>= T16, ties included); exact np p computed here.
    const float* x0 = xmap + (size_t)b * 2 * H * W;
    const float* x1 = x0 + (size_t)H * W;
    if (threadIdx.x < 256) outb[threadIdx.x] = 0;
    __syncthreads();
    for (int t = threadIdx.x; t < n; t += TPB) {
        uint64_t e = list[t];
        if ((uint32_t)(e >> 32) >= T16) {
            int pos = atomicAdd(&s_out, 1);
            if (pos < 256) {
                int gidx = (int)(uint32_t)e;
                float D = __fsub_rn(x1[gidx], x0[gidx]);
                float p = G_exact(D);
                outb[pos] = ((uint64_t)__float_as_uint(p) << 32) | (uint32_t)(~gidx);
            }
        }
    }
    __syncthreads();
    bitonic_sort_256(outb);

    // Decode top-100 (exact (p desc, idx asc) order).
    if (threadIdx.x < KTOP) {
        uint64_t k = outb[threadIdx.x];
        int id = (int)(~(uint32_t)k);
        float o0 = 0.f, o1 = 0.f, o2 = 0.f, o3 = 0.f, val = 0.f;
        if ((unsigned)id < (unsigned)(H * W)) {
            val = __uint_as_float((uint32_t)(k >> 32));
            int yy = id / W, xx = id - yy * W;             // compile-time divisor
            constexpr float ds = BALL ? 4.0f : 16.0f;
            float xc = (float)xx * ds + (ds - 1.0f) * 0.5f;
            float yc = (float)yy * ds + (ds - 1.0f) * 0.5f;
            float t0 = 0.f, t1 = 0.f;
            float t2 = BALL ? 40.0f : 0.0f, t3 = BALL ? 40.0f : 0.0f;
            if (!BALL) {
                const float* bb = pbbox + (size_t)b * 4 * H * W;
                constexpr float sx = (float)W * ds, sy = (float)H * ds;
                t0 = bb[id]             * sx;
                t1 = bb[id + H * W]     * sy;
                t2 = bb[id + 2 * H * W] * sx;
                t3 = bb[id + 3 * H * W] * sy;
            }
            float bx = xc + t0, by = yc + t1;
            o0 = bx - 0.5f * t2;
            o1 = by - 0.5f * t3;
            o2 = bx + 0.5f * t2;
            o3 = by + 0.5f * t3;
        }
        float* op = outp + (size_t)threadIdx.x * 5;
        op[0] = o0; op[1] = o1; op[2] = o2; op[3] = o3; op[4] = val;
    }
}

__global__ __launch_bounds__(TPB) void stage2(const float* __restrict__ bmap,
                                              const float* __restrict__ pmap,
                                              const float* __restrict__ pbbox,
                                              const uint32_t* __restrict__ cnts,
                                              const uint64_t* __restrict__ blist,
                                              const uint64_t* __restrict__ plist,
                                              float* __restrict__ out)
{
    __shared__ uint32_t hist[256];
    __shared__ uint64_t outb[256];
    if (blockIdx.x < NB) {
        int b = blockIdx.x;
        stage2_impl<HB, WB, true>(bmap, nullptr, cnts + b,
            blist + (size_t)b * BLCAP,
            out + (size_t)NB * KTOP * 5 + (size_t)b * KTOP * 5, b, hist, outb);
    } else {
        int b = blockIdx.x - NB;
        stage2_impl<HP, WP, false>(pmap, pbbox, cnts + NB + b,
            plist + (size_t)b * PLCAP,
            out + (size_t)b * KTOP * 5, b, hist, outb);
    }
}

// ---- launch -----------------------------------------------------------------
extern "C" void kernel_launch(void* const* d_in, const int* in_sizes, int n_in,
                              void* d_out, int out_size, void* d_ws, size_t ws_size,
                              hipStream_t stream) {
    const float* pmap  = (const float*)d_in[0];   // [64,2,68,120]
    const float* pbbox = (const float*)d_in[1];   // [64,4,68,120]
    const float* bmap  = (const float*)d_in[2];   // [64,2,272,480]
    float* out = (float*)d_out;                   // player [64,100,5] then ball

    uint32_t* cnts  = (uint32_t*)d_ws;                         // 128 counters
    uint64_t* blist = (uint64_t*)((char*)d_ws + 1024);         // 64*32768 u64
    uint64_t* plist = blist + (size_t)NB * BLCAP;              // 64*8192 u64
    // ws usage: 1024 + 16.78 MB + 4.19 MB ~= 21 MB

    zeroK<<<1, 128, 0, stream>>>(cnts);
    stage1<<<dim3(NSB + NSP, NB), TPB, 0, stream>>>(bmap, pmap, cnts, blist, plist);
    stage2<<<2 * NB, TPB, 0, stream>>>(bmap, pmap, pbbox, cnts, blist, plist, out);
}

// Round 8
// 152.335 us; speedup vs baseline: 7.4071x; 7.4071x over previous
//
#include <hip/hip_runtime.h>
#include <stdint.h>
#include <math.h>

#define TPB   512    // 8 waves/block -> 4 blocks/CU at the 32-wave cap
#define KTOP  100
#define K1    128    // per-image selection rank cut
#define CAP   768    // stage-1 per-slice LDS survivor capacity (~453 expected max)
#define SR    8      // slice rows

#define HB 272
#define WB 480
#define NSB 34       // 272/8
#define HP 68
#define WP 120
#define NSP 9        // ceil(68/8), last slice 4 rows
#define NB 64

#define BLCAP 32768  // per-image ball survivor list capacity (~15.3k expected)
#define PLCAP 8192   // per-image player survivor list capacity (~0.9k expected)
#define CSTRIDE 32   // counter stride in u32 = 128 B (one cache line each)

// ============================================================================
// Validated invariants (rounds 2-6, absmax 0.0):
//  - np-f32 softmax p is a MONOTONE function G of D = fl32(x1-x0);
//    G collapse window |dD| < ~6e-8*e^|D| (< 0.25 for |D| < 13).
//  - NMS: keep iff p >= all 8 neighbors; D-space fast path + exact G on ties.
//  - top-k tie order: (p desc, idx asc)  ==  u64 key (p_bits<<32 | ~idx) desc.
//  - 16-bit D-key rank-128 cut (ties included) contains the exact top-100 set.
// Round-7 lesson: NO per-element global atomics on shared cache lines —
// reserve list space with ONE block-level atomic on a padded counter.
// ============================================================================
__device__ __forceinline__ float G_exact(float D) {
    float t = -fabsf(D);
    float etf = (float)exp((double)t);       // correctly-rounded f32 exp
    return (D > 0.0f) ? __fdiv_rn(1.0f, __fadd_rn(etf, 1.0f))
                      : __fdiv_rn(etf, __fadd_rn(1.0f, etf));
}

__device__ __forceinline__ uint32_t flip_f32(float D) {
    uint32_t u = __float_as_uint(D);
    return (u & 0x80000000u) ? ~u : (u | 0x80000000u);
}

// In-place suffix-sum of 256 u32 bins: hist[i] <- sum_{j>=i} hist[j].
// Wave 0 via shuffles; ends with a barrier. (validated round 4)
__device__ __forceinline__ void suffix_scan_256(uint32_t* hist) {
    if (threadIdx.x < 64) {
        int lane = threadIdx.x;
        uint32_t h0 = hist[4*lane+0], h1 = hist[4*lane+1];
        uint32_t h2 = hist[4*lane+2], h3 = hist[4*lane+3];
        uint32_t tot = h0 + h1 + h2 + h3;
        uint32_t run = tot;
        #pragma unroll
        for (int d = 1; d < 64; d <<= 1) {
            uint32_t o = __shfl_down(run, d, 64);
            if (lane + d < 64) run += o;
        }
        uint32_t ab = run - tot;
        hist[4*lane+3] = ab + h3;
        hist[4*lane+2] = ab + h3 + h2;
        hist[4*lane+1] = ab + h3 + h2 + h1;
        hist[4*lane+0] = ab + tot;
    }
    __syncthreads();
}

// Descending bitonic sort of 256 u64 keys; TPB may exceed 256 (guarded).
__device__ void bitonic_sort_256(uint64_t* keys) {
    for (int k = 2; k <= 256; k <<= 1) {
        for (int j = k >> 1; j > 0; j >>= 1) {
            int i = threadIdx.x;
            if (i < 256) {
                int ixj = i ^ j;
                if (ixj > i) {
                    uint64_t ka = keys[i], kb = keys[ixj];
                    bool sw = ((ka < kb) == ((i & k) == 0));
                    if (sw) { keys[i] = kb; keys[ixj] = ka; }
                }
            }
            __syncthreads();
        }
    }
}

// 6-wide row window [c4-1 .. c4+4] from the LDS D-tile (OOB -> -inf).
template<int W>
__device__ __forceinline__ void row6(const float* df, int row, int c4, float* a) {
    const float4 m = ((const float4*)df)[(row * W + c4) >> 2];
    a[1] = m.x; a[2] = m.y; a[3] = m.z; a[4] = m.w;
    a[0] = (c4 > 0)     ? df[row * W + c4 - 1] : -INFINITY;
    a[5] = (c4 + 4 < W) ? df[row * W + c4 + 4] : -INFINITY;
}

// ---- init: zero the padded per-image append counters -----------------------
__global__ void zeroK(uint32_t* cnts) {
    for (int t = threadIdx.x; t < 128 * CSTRIDE; t += TPB) cnts[t] = 0;
}

// ---- stage 1: D-tile NMS -> LDS survivors -> 1 atomic chunk reserve --------
template<int H, int W>
__device__ __forceinline__ void stage1_impl(const float* __restrict__ x,
                                            int s, int b,
                                            uint32_t* __restrict__ cnt,
                                            uint64_t* __restrict__ list,
                                            int lcap, float* df, uint32_t* surv)
{
    constexpr int W4 = W / 4;
    constexpr int tileRows = SR + 2;
    const int r0 = s * SR;
    const int rows = (H - r0 < SR) ? (H - r0) : SR;

    __shared__ int s_cnt, s_base;
    if (threadIdx.x == 0) s_cnt = 0;

    const float*  x0  = x + (size_t)b * 2 * H * W;
    const float*  x1  = x0 + (size_t)H * W;
    const float4* x0v = (const float4*)x0;
    const float4* x1v = (const float4*)x1;
    float4* dfv = (float4*)df;

    // D tile (rows r0-1 .. r0+SR), float4-vectorized; OOB rows -> -inf.
    constexpr int nt4 = tileRows * W4;
    for (int t = threadIdx.x; t < nt4; t += TPB) {
        int tr = t / W4, c4 = t - tr * W4;        // compile-time divisor
        int r = r0 - 1 + tr;
        float4 d4 = make_float4(-INFINITY, -INFINITY, -INFINITY, -INFINITY);
        if (r >= 0 && r < H) {
            float4 a = x0v[r * W4 + c4];
            float4 c = x1v[r * W4 + c4];
            d4.x = __fsub_rn(c.x, a.x);
            d4.y = __fsub_rn(c.y, a.y);
            d4.z = __fsub_rn(c.z, a.z);
            d4.w = __fsub_rn(c.w, a.w);
        }
        dfv[t] = d4;
    }
    __syncthreads();

    // NMS (4 cells/iter), separable column-max; survivors -> LDS (LDS atomic).
    const int groups = rows * W4;
    for (int g = threadIdx.x; g < groups; g += TPB) {
        int lr = g / W4, c4 = (g - lr * W4) << 2; // compile-time divisor
        int tr = lr + 1;
        float ap[6], ac[6], an[6], cm[6];
        row6<W>(df, tr - 1, c4, ap);
        row6<W>(df, tr,     c4, ac);
        row6<W>(df, tr + 1, c4, an);
        #pragma unroll
        for (int i = 0; i < 6; ++i) cm[i] = fmaxf(fmaxf(ap[i], ac[i]), an[i]);
        #pragma unroll
        for (int j = 0; j < 4; ++j) {
            float v = ac[j + 1];
            float mx = fmaxf(fmaxf(cm[j], cm[j + 2]), fmaxf(ap[j + 1], an[j + 1]));
            bool keep;
            if (v >= mx) keep = true;                              // exact
            else if (mx - v >= 0.25f && mx < 13.0f) keep = false;  // G distinct
            else keep = (G_exact(v) == G_exact(mx));               // rare tie
            if (keep) {
                uint32_t key16 = flip_f32(v) >> 16;
                int pos = atomicAdd(&s_cnt, 1);
                if (pos < CAP)
                    surv[pos] = (key16 << 16) | ((uint32_t)lr << 9) | (uint32_t)(c4 + j);
            }
        }
    }
    __syncthreads();

    // One global atomic per block reserves a contiguous chunk.
    const int n = (s_cnt < CAP) ? s_cnt : CAP;
    if (threadIdx.x == 0) s_base = (int)atomicAdd(cnt, (uint32_t)n);
    __syncthreads();
    const int base = s_base;

    // Coalesced write-out: expand u32 survivor -> u64 (key16<<32 | gidx).
    for (int t = threadIdx.x; t < n; t += TPB) {
        uint32_t sv = surv[t];
        int lr = (sv >> 9) & 7, c = sv & 511;
        uint32_t gidx = (uint32_t)((r0 + lr) * W + c);
        int dst = base + t;
        if (dst < lcap) list[dst] = ((uint64_t)(sv >> 16) << 32) | gidx;
    }
}

__global__ __launch_bounds__(TPB) void stage1(const float* __restrict__ bmap,
                                              const float* __restrict__ pmap,
                                              uint32_t* __restrict__ cnts,
                                              uint64_t* __restrict__ blist,
                                              uint64_t* __restrict__ plist)
{
    __shared__ float df[(SR + 2) * WB];           // 19200 B (max of both maps)
    __shared__ uint32_t surv[CAP];                // 3072 B
    const int b = blockIdx.y;
    if (blockIdx.x < NSB)
        stage1_impl<HB, WB>(bmap, blockIdx.x, b, cnts + (size_t)b * CSTRIDE,
                            blist + (size_t)b * BLCAP, BLCAP, df, surv);
    else
        stage1_impl<HP, WP>(pmap, blockIdx.x - NSB, b,
                            cnts + (size_t)(NB + b) * CSTRIDE,
                            plist + (size_t)b * PLCAP, PLCAP, df, surv);
}

// ---- stage 2: per-image D16 radix-select -> exact-p rerank -> decode -------
template<int H, int W, bool BALL>
__device__ __forceinline__ void stage2_impl(const float* __restrict__ xmap,
                                            const float* __restrict__ pbbox,
                                            const uint32_t* __restrict__ cnt,
                                            const uint64_t* __restrict__ list,
                                            float* __restrict__ outp, int b,
                                            uint32_t* hist, uint64_t* outb)
{
    __shared__ int s_out;
    __shared__ uint32_t s_bin, s_ab, s_bin2, s_none;
    if (threadIdx.x == 0) { s_out = 0; s_none = 0; }
    if (threadIdx.x < 256) hist[threadIdx.x] = 0;
    __syncthreads();

    const int n = min((int)*cnt, BALL ? BLCAP : PLCAP);

    // Level-1: histogram of key16 high byte.
    for (int t = threadIdx.x; t < n; t += TPB) {
        uint32_t k16 = (uint32_t)(list[t] >> 32);
        atomicAdd(&hist[k16 >> 8], 1u);
    }
    __syncthreads();
    suffix_scan_256(hist);
    if (threadIdx.x < 256) {
        uint32_t si = hist[threadIdx.x];
        uint32_t sn = (threadIdx.x < 255) ? hist[threadIdx.x + 1] : 0u;
        if (threadIdx.x == 0 && si < K1) s_none = 1;
        if (si >= K1 && sn < K1) { s_bin = threadIdx.x; s_ab = sn; }
    }
    __syncthreads();

    uint32_t T16 = 0;
    if (!s_none) {
        const uint32_t b3 = s_bin;
        const uint32_t k2 = K1 - s_ab;
        if (threadIdx.x < 256) hist[threadIdx.x] = 0;
        __syncthreads();
        for (int t = threadIdx.x; t < n; t += TPB) {
            uint32_t k16 = (uint32_t)(list[t] >> 32);
            if ((k16 >> 8) == b3) atomicAdd(&hist[k16 & 255u], 1u);
        }
        __syncthreads();
        suffix_scan_256(hist);
        if (threadIdx.x < 256) {
            uint32_t si = hist[threadIdx.x];
            uint32_t sn = (threadIdx.x < 255) ? hist[threadIdx.x + 1] : 0u;
            if (si >= k2 && sn < k2) s_bin2 = threadIdx.x;
        }
        __syncthreads();
        T16 = (b3 << 8) | s_bin2;
    }

    // Compact finalists (>= T16, ties included); exact np p computed here.
    const float* x0 = xmap + (size_t)b * 2 * H * W;
    const float* x1 = x0 + (size_t)H * W;
    if (threadIdx.x < 256) outb[threadIdx.x] = 0;
    __syncthreads();
    for (int t = threadIdx.x; t < n; t += TPB) {
        uint64_t e = list[t];
        if ((uint32_t)(e >> 32) >= T16) {
            int pos = atomicAdd(&s_out, 1);
            if (pos < 256) {
                int gidx = (int)(uint32_t)e;
                float D = __fsub_rn(x1[gidx], x0[gidx]);
                float p = G_exact(D);
                outb[pos] = ((uint64_t)__float_as_uint(p) << 32) | (uint32_t)(~gidx);
            }
        }
    }
    __syncthreads();
    bitonic_sort_256(outb);

    // Decode top-100 (exact (p desc, idx asc) order).
    if (threadIdx.x < KTOP) {
        uint64_t k = outb[threadIdx.x];
        int id = (int)(~(uint32_t)k);
        float o0 = 0.f, o1 = 0.f, o2 = 0.f, o3 = 0.f, val = 0.f;
        if ((unsigned)id < (unsigned)(H * W)) {
            val = __uint_as_float((uint32_t)(k >> 32));
            int yy = id / W, xx = id - yy * W;             // compile-time divisor
            constexpr float ds = BALL ? 4.0f : 16.0f;
            float xc = (float)xx * ds + (ds - 1.0f) * 0.5f;
            float yc = (float)yy * ds + (ds - 1.0f) * 0.5f;
            float t0 = 0.f, t1 = 0.f;
            float t2 = BALL ? 40.0f : 0.0f, t3 = BALL ? 40.0f : 0.0f;
            if (!BALL) {
                const float* bb = pbbox + (size_t)b * 4 * H * W;
                constexpr float sx = (float)W * ds, sy = (float)H * ds;
                t0 = bb[id]             * sx;
                t1 = bb[id + H * W]     * sy;
                t2 = bb[id + 2 * H * W] * sx;
                t3 = bb[id + 3 * H * W] * sy;
            }
            float bx = xc + t0, by = yc + t1;
            o0 = bx - 0.5f * t2;
            o1 = by - 0.5f * t3;
            o2 = bx + 0.5f * t2;
            o3 = by + 0.5f * t3;
        }
        float* op = outp + (size_t)threadIdx.x * 5;
        op[0] = o0; op[1] = o1; op[2] = o2; op[3] = o3; op[4] = val;
    }
}

__global__ __launch_bounds__(TPB) void stage2(const float* __restrict__ bmap,
                                              const float* __restrict__ pmap,
                                              const float* __restrict__ pbbox,
                                              const uint32_t* __restrict__ cnts,
                                              const uint64_t* __restrict__ blist,
                                              const uint64_t* __restrict__ plist,
                                              float* __restrict__ out)
{
    __shared__ uint32_t hist[256];
    __shared__ uint64_t outb[256];
    if (blockIdx.x < NB) {
        int b = blockIdx.x;
        stage2_impl<HB, WB, true>(bmap, nullptr, cnts + (size_t)b * CSTRIDE,
            blist + (size_t)b * BLCAP,
            out + (size_t)NB * KTOP * 5 + (size_t)b * KTOP * 5, b, hist, outb);
    } else {
        int b = blockIdx.x - NB;
        stage2_impl<HP, WP, false>(pmap, pbbox, cnts + (size_t)(NB + b) * CSTRIDE,
            plist + (size_t)b * PLCAP,
            out + (size_t)b * KTOP * 5, b, hist, outb);
    }
}

// ---- launch -----------------------------------------------------------------
extern "C" void kernel_launch(void* const* d_in, const int* in_sizes, int n_in,
                              void* d_out, int out_size, void* d_ws, size_t ws_size,
                              hipStream_t stream) {
    const float* pmap  = (const float*)d_in[0];   // [64,2,68,120]
    const float* pbbox = (const float*)d_in[1];   // [64,4,68,120]
    const float* bmap  = (const float*)d_in[2];   // [64,2,272,480]
    float* out = (float*)d_out;                   // player [64,100,5] then ball

    uint32_t* cnts  = (uint32_t*)d_ws;                         // 128 x 128B
    uint64_t* blist = (uint64_t*)((char*)d_ws + 128 * CSTRIDE * 4);
    uint64_t* plist = blist + (size_t)NB * BLCAP;
    // ws usage: 16 KB + 16.78 MB + 4.19 MB ~= 21 MB

    zeroK<<<1, TPB, 0, stream>>>(cnts);
    stage1<<<dim3(NSB + NSP, NB), TPB, 0, stream>>>(bmap, pmap, cnts, blist, plist);
    stage2<<<2 * NB, TPB, 0, stream>>>(bmap, pmap, pbbox, cnts, blist, plist, out);
}